// Round 1
// baseline (11045.657 us; speedup 1.0000x reference)
//
#include <hip/hip_runtime.h>

// Problem: N=4096, V=50000, D=64, EPS=1e-7 (keras SparseCategoricalCrossentropy)
#define NROWS 4096
#define VOCAB 50000
#define DIM   64
#define EPS   1e-7f

constexpr int TPB = 256;
constexpr int BM  = 64;    // rows per block
constexpr int BV  = 128;   // vocab cols per block
constexpr int NVT = (VOCAB + BV - 1) / BV;   // 391 v-tiles (last has 80 valid)
constexpr int LDA = DIM + 4;  // 68 words: float4-aligned rows, broadcast reads
constexpr int LDB = DIM + 4;  // 68 words: lane-stride 68 ≡ 4 mod 32 -> 4-way worst case

// ---------------------------------------------------------------------------
// K0: zero the per-row z accumulators (atomicAdd targets).
// ---------------------------------------------------------------------------
__global__ __launch_bounds__(TPB) void k0_zero(float* __restrict__ zrow)
{
    int i = blockIdx.x * TPB + threadIdx.x;
    if (i < NROWS) zrow[i] = 0.f;
}

// ---------------------------------------------------------------------------
// K1: logits = inputs @ emb^T written to out; z[row] += sum_v exp(logit).
// No max-subtraction: logits are O(1) for this problem, exp() is safe and
// branch-free. Grid: (64 row-bands, 391 v-tiles); x fastest so consecutive
// blocks share the same B tile (L2-hot).
// Tile 64x128, thread tile 8 rows x 4 cols. rg = tid>>5 (half-wave shares
// rows -> A reads broadcast), vg = tid&31, thread cols v0+vg+{0,32,64,96}
// (lane-consecutive -> coalesced stores).
// ---------------------------------------------------------------------------
__global__ __launch_bounds__(TPB, 3) void k1_gemm(
    const float* __restrict__ inp, const float* __restrict__ emb,
    float* __restrict__ out, float* __restrict__ zrow)
{
    __shared__ float a_s[BM][LDA];   // 17408 B
    __shared__ float b_s[BV][LDB];   // 34816 B  (52 KB total -> 3 blocks/CU)

    const int tid   = threadIdx.x;
    const int rbase = blockIdx.x * BM;
    const int v0    = blockIdx.y * BV;
    const int rg    = tid >> 5;   // 0..7: row group (8 rows each)
    const int vg    = tid & 31;   // 0..31: lane within half-wave

    // Stage A: 64 rows x 16 float4 = 1024 float4, 4 per thread, coalesced.
    {
        const float4* g = (const float4*)(inp + (size_t)rbase * DIM);
        #pragma unroll
        for (int k = 0; k < 4; ++k) {
            int i = tid + k * TPB;
            int r = i >> 4, c = i & 15;
            ((float4*)&a_s[r][0])[c] = g[i];
        }
    }
    // Stage B: 128 rows x 16 float4 = 2048 float4, 8 per thread.
    const bool full = (v0 + BV <= VOCAB);
    if (full) {
        const float4* g = (const float4*)(emb + (size_t)v0 * DIM);
        #pragma unroll
        for (int k = 0; k < 8; ++k) {
            int i = tid + k * TPB;
            int r = i >> 4, c = i & 15;
            ((float4*)&b_s[r][0])[c] = g[i];
        }
    } else {
        #pragma unroll
        for (int k = 0; k < 8; ++k) {
            int i = tid + k * TPB;
            int r = i >> 4, c = i & 15;
            float4 val = make_float4(0.f, 0.f, 0.f, 0.f);
            if (v0 + r < VOCAB)
                val = ((const float4*)(emb + (size_t)(v0 + r) * DIM))[c];
            ((float4*)&b_s[r][0])[c] = val;
        }
    }
    __syncthreads();

    float acc[8][4];
    #pragma unroll
    for (int i = 0; i < 8; ++i)
        #pragma unroll
        for (int j = 0; j < 4; ++j) acc[i][j] = 0.f;

    // 2048 FMA vs 192 ds_read_b128 per thread: 10.7:1 issue ratio.
    #pragma unroll
    for (int d4 = 0; d4 < DIM / 4; ++d4) {
        float4 b4[4];
        #pragma unroll
        for (int j = 0; j < 4; ++j)
            b4[j] = *(const float4*)&b_s[vg + 32 * j][d4 * 4];
        float4 a4[8];
        #pragma unroll
        for (int i = 0; i < 8; ++i)
            a4[i] = *(const float4*)&a_s[rg * 8 + i][d4 * 4];  // broadcast
        #pragma unroll
        for (int i = 0; i < 8; ++i)
            #pragma unroll
            for (int j = 0; j < 4; ++j) {
                acc[i][j] = fmaf(a4[i].x, b4[j].x, acc[i][j]);
                acc[i][j] = fmaf(a4[i].y, b4[j].y, acc[i][j]);
                acc[i][j] = fmaf(a4[i].z, b4[j].z, acc[i][j]);
                acc[i][j] = fmaf(a4[i].w, b4[j].w, acc[i][j]);
            }
    }

    // Store logits (coalesced: lanes 0..31 cover 128 contiguous bytes) and
    // accumulate z = sum exp(logit) per row; branch-free on full tiles.
    #pragma unroll
    for (int i = 0; i < 8; ++i) {
        const int r = rbase + rg * 8 + i;
        float* rowp = out + (size_t)r * VOCAB + v0 + vg;
        float zp = 0.f;
        if (full) {
            #pragma unroll
            for (int j = 0; j < 4; ++j) {
                const float x = acc[i][j];
                rowp[32 * j] = x;
                zp += __expf(x);
            }
        } else {
            #pragma unroll
            for (int j = 0; j < 4; ++j) {
                if (v0 + vg + 32 * j < VOCAB) {
                    const float x = acc[i][j];
                    rowp[32 * j] = x;
                    zp += __expf(x);
                }
            }
        }
        // Reduce across the 32 lanes of this half-wave (same 8 rows).
        zp += __shfl_xor(zp, 16);
        zp += __shfl_xor(zp, 8);
        zp += __shfl_xor(zp, 4);
        zp += __shfl_xor(zp, 2);
        zp += __shfl_xor(zp, 1);
        if (vg == 0) atomicAdd(&zrow[r], zp);
    }
}

// ---------------------------------------------------------------------------
// K3: logits -> probs in place; per-row clipped sum S and loss term
// log(S) - log(clip(p[label])). One block per row, BW-bound.
// ---------------------------------------------------------------------------
__global__ __launch_bounds__(TPB) void k3_probs(
    float* __restrict__ out, const float* __restrict__ zrow,
    const int* __restrict__ label, float* __restrict__ lossPart)
{
    const int n = blockIdx.x;
    const float iz = 1.f / zrow[n];
    const float hi = 1.0f - EPS;
    const int lab = label[n];
    const int li = lab >> 2;
    const int lc = lab & 3;
    __shared__ float plab;
    __shared__ float red[4];

    float4* p = (float4*)(out + (size_t)n * VOCAB);
    float s = 0.f;
    for (int i = threadIdx.x; i < VOCAB / 4; i += TPB) {
        float4 l = p[i];
        float4 q;
        q.x = __expf(l.x) * iz;
        q.y = __expf(l.y) * iz;
        q.z = __expf(l.z) * iz;
        q.w = __expf(l.w) * iz;
        p[i] = q;
        s += fminf(fmaxf(q.x, EPS), hi);
        s += fminf(fmaxf(q.y, EPS), hi);
        s += fminf(fmaxf(q.z, EPS), hi);
        s += fminf(fmaxf(q.w, EPS), hi);
        if (i == li)  // exactly one thread/iteration hits the label element
            plab = (lc == 0) ? q.x : (lc == 1) ? q.y : (lc == 2) ? q.z : q.w;
    }
    for (int off = 32; off; off >>= 1) s += __shfl_down(s, off);
    if ((threadIdx.x & 63) == 0) red[threadIdx.x >> 6] = s;
    __syncthreads();
    if (threadIdx.x == 0) {
        const float S = red[0] + red[1] + red[2] + red[3];
        const float pl = fminf(fmaxf(plab, EPS), hi);
        lossPart[n] = logf(S) - logf(pl);
    }
}

// ---------------------------------------------------------------------------
// K4: loss = mean(lossPart)
// ---------------------------------------------------------------------------
__global__ __launch_bounds__(TPB) void k4_loss(
    const float* __restrict__ lossPart, float* __restrict__ lossOut)
{
    float acc = 0.f;
    for (int n = threadIdx.x; n < NROWS; n += TPB) acc += lossPart[n];
    for (int off = 32; off; off >>= 1) acc += __shfl_down(acc, off);
    __shared__ float red[4];
    if ((threadIdx.x & 63) == 0) red[threadIdx.x >> 6] = acc;
    __syncthreads();
    if (threadIdx.x == 0)
        lossOut[0] = (red[0] + red[1] + red[2] + red[3]) / (float)NROWS;
}

extern "C" void kernel_launch(void* const* d_in, const int* in_sizes, int n_in,
                              void* d_out, int out_size, void* d_ws, size_t ws_size,
                              hipStream_t stream)
{
    const int*   label = (const int*)d_in[0];   // int32 (jax x64 disabled)
    const float* inp   = (const float*)d_in[1]; // [4096, 64]
    const float* emb   = (const float*)d_in[2]; // [50000, 64]
    float* out = (float*)d_out;                 // [4096*50000] probs + [1] loss

    // Workspace: zrow[4096], lossPart[4096]  (32 KB)
    float* zrow     = (float*)d_ws;
    float* lossPart = zrow + NROWS;

    k0_zero<<<(NROWS + TPB - 1) / TPB, TPB, 0, stream>>>(zrow);
    dim3 g1(NROWS / BM, NVT);   // x fastest: consecutive blocks share B tile
    k1_gemm<<<g1, TPB, 0, stream>>>(inp, emb, out, zrow);
    k3_probs<<<NROWS, TPB, 0, stream>>>(out, zrow, label, lossPart);
    k4_loss<<<1, TPB, 0, stream>>>(lossPart, out + (size_t)NROWS * VOCAB);
}